// Round 1
// baseline (28043.985 us; speedup 1.0000x reference)
//
#include <hip/hip_runtime.h>
#include <hip/hip_cooperative_groups.h>

namespace cg = cooperative_groups;

#define Bdim 128
#define Tdim 256
#define Hdim 512
#define INdim 300
#define KXdim 320   // K=300 padded to mult of 16
#define NC 45
#define LNEPS 1e-5f
#define NBLK 256
#define NTHR 256

__device__ __forceinline__ float fast_tanh(float v) {
    float e = __expf(2.0f * v);
    return 1.0f - 2.0f / (e + 1.0f);
}

struct RnnArgs {
    const float* x0;      // x (l2r)
    const float* x1;      // reverse_x (r2l)
    const float* Wx[2];   // [3][H][H]
    const float* Wh[2];   // [3][H][H]
    const float* lng;     // [3][H]
    const float* lnb;     // [3][H]
    const float* W0;      // [2][KX][H]  fused W_emb@Wx0 (rows >=300 zero)
    const float* cb;      // [2][3][H]   fused biases
    float* h2;            // [2][T][B][H] layer-2 outputs
    float* hs;            // [2][3][2][B][H] state ring
    float* zb;            // [6][B][H] raw z
    float* ps;            // [6][B][8] partial sums
    float* pq;            // [6][B][8] partial sumsq
};

// Fuse W0 = W_emb @ Wx[dir][0]  (padded to KX rows), cb = fused biases
__global__ __launch_bounds__(NTHR) void prep_kernel(
    const float* Wemb, const float* bemb,
    const float* Wx_l2r, const float* bx_l2r, const float* bh_l2r,
    const float* Wx_r2l, const float* bx_r2l, const float* bh_r2l,
    float* W0, float* cb)
{
    int gid = blockIdx.x * NTHR + threadIdx.x;
    const int nW0 = 2 * KXdim * Hdim;
    if (gid < nW0) {
        int dir = gid / (KXdim * Hdim);
        int rem = gid % (KXdim * Hdim);
        int i = rem / Hdim, h = rem % Hdim;
        const float* Wx = dir ? Wx_r2l : Wx_l2r;  // layer 0 block
        float s = 0.f;
        if (i < INdim) {
            for (int k = 0; k < Hdim; ++k)
                s += Wemb[i * Hdim + k] * Wx[k * Hdim + h];
        }
        W0[gid] = s;
    } else {
        int idx = gid - nW0;
        if (idx < 2 * 3 * Hdim) {
            int dir = idx / (3 * Hdim);
            int l = (idx / Hdim) % 3;
            int h = idx % Hdim;
            const float* Wx = dir ? Wx_r2l : Wx_l2r;
            const float* bx = dir ? bx_r2l : bx_l2r;
            const float* bh = dir ? bh_r2l : bh_l2r;
            float s = bx[l * Hdim + h] + bh[l * Hdim + h];
            if (l == 0) {  // + b_emb @ Wx0
                for (int k = 0; k < Hdim; ++k)
                    s += bemb[k] * Wx[k * Hdim + h];
            }
            cb[idx] = s;
        }
    }
}

__global__ __launch_bounds__(NTHR) void rnn_coop(RnnArgs a) {
    cg::grid_group grid = cg::this_grid();
    const int blk = blockIdx.x, tid = threadIdx.x;

    // zero the state ring (ws is poisoned 0xAA each launch)
    {
        const int n = 2 * 3 * 2 * Bdim * Hdim;
        for (int i = blk * NTHR + tid; i < n; i += NBLK * NTHR) a.hs[i] = 0.f;
    }
    grid.sync();

    __shared__ float sA[32 * 17];
    __shared__ float sB[16 * 64];

    // unit = blk & 7 pins each layer-unit to one XCD (blockIdx % 8 swizzle);
    // units 6,7 -> idle in G phase (still help in F phase)
    const int u = blk & 7;
    const bool worker = (u < 6);
    const int widx = blk >> 3;          // 0..31 within unit
    const int rt = widx >> 3;           // 0..3  row tile (32 rows)
    const int ct = widx & 7;            // 0..7  col tile (64 cols)
    const int dir = u / 3, lay = u % 3;
    const int r0 = rt * 32, h0 = ct * 64;
    const int ty = tid >> 4, tx = tid & 15;

    for (int s = 0; s < Tdim + 2; ++s) {
        const int t = s - lay;
        const int ps_ = (s - 1) & 1;    // read slot
        if (worker && t >= 0 && t < Tdim) {
            float acc[2][4] = {{0,0,0,0},{0,0,0,0}};
            for (int src = 0; src < 2; ++src) {
                const float* inbase; int instride, K, kg; const float* W;
                if (lay == 0 && src == 0) {
                    inbase = (dir ? a.x1 : a.x0) + t * INdim;
                    instride = Tdim * INdim; K = KXdim; kg = INdim;
                    W = a.W0 + dir * KXdim * Hdim;
                } else {
                    int sl = (src == 0) ? (lay - 1) : lay;
                    inbase = a.hs + ((dir * 3 + sl) * 2 + ps_) * (Bdim * Hdim);
                    instride = Hdim; K = Hdim; kg = Hdim;
                    W = ((src == 0) ? a.Wx[dir] : a.Wh[dir]) + lay * Hdim * Hdim;
                }
                for (int k0 = 0; k0 < K; k0 += 16) {
                    {   // stage A: 32 rows x 16 k
                        int rr = tid >> 3;
                        int kk = (tid & 7) * 2;
                        int row = r0 + rr;
                        int ka = k0 + kk;
                        float v0 = (ka     < kg) ? inbase[row * instride + ka]     : 0.f;
                        float v1 = (ka + 1 < kg) ? inbase[row * instride + ka + 1] : 0.f;
                        sA[rr * 17 + kk]     = v0;
                        sA[rr * 17 + kk + 1] = v1;
                    }
                    {   // stage B: 16 k x 64 cols
                        int kk = tid >> 4;
                        int c4 = (tid & 15) * 4;
                        float4 wv = *(const float4*)(W + (k0 + kk) * Hdim + h0 + c4);
                        *(float4*)&sB[kk * 64 + c4] = wv;
                    }
                    __syncthreads();
                    #pragma unroll
                    for (int kk = 0; kk < 16; ++kk) {
                        float a0 = sA[ty * 17 + kk];
                        float a1 = sA[(ty + 16) * 17 + kk];
                        float4 bv = *(const float4*)&sB[kk * 64 + tx * 4];
                        acc[0][0] += a0 * bv.x; acc[0][1] += a0 * bv.y;
                        acc[0][2] += a0 * bv.z; acc[0][3] += a0 * bv.w;
                        acc[1][0] += a1 * bv.x; acc[1][1] += a1 * bv.y;
                        acc[1][2] += a1 * bv.z; acc[1][3] += a1 * bv.w;
                    }
                    __syncthreads();
                }
            }
            // add fused bias, write raw z, per-row partial stats
            const float4 cbv = *(const float4*)&a.cb[(dir * 3 + lay) * Hdim + h0 + tx * 4];
            float zsum[2], zsq[2];
            #pragma unroll
            for (int i = 0; i < 2; ++i) {
                acc[i][0] += cbv.x; acc[i][1] += cbv.y;
                acc[i][2] += cbv.z; acc[i][3] += cbv.w;
                int row = r0 + ty + i * 16;
                float4 zv = make_float4(acc[i][0], acc[i][1], acc[i][2], acc[i][3]);
                *(float4*)&a.zb[(u * Bdim + row) * Hdim + h0 + tx * 4] = zv;
                zsum[i] = acc[i][0] + acc[i][1] + acc[i][2] + acc[i][3];
                zsq[i]  = acc[i][0]*acc[i][0] + acc[i][1]*acc[i][1]
                        + acc[i][2]*acc[i][2] + acc[i][3]*acc[i][3];
            }
            #pragma unroll
            for (int m = 1; m < 16; m <<= 1) {
                zsum[0] += __shfl_xor(zsum[0], m, 16);
                zsum[1] += __shfl_xor(zsum[1], m, 16);
                zsq[0]  += __shfl_xor(zsq[0],  m, 16);
                zsq[1]  += __shfl_xor(zsq[1],  m, 16);
            }
            if (tx == 0) {
                a.ps[(u * Bdim + r0 + ty) * 8 + ct]      = zsum[0];
                a.ps[(u * Bdim + r0 + ty + 16) * 8 + ct] = zsum[1];
                a.pq[(u * Bdim + r0 + ty) * 8 + ct]      = zsq[0];
                a.pq[(u * Bdim + r0 + ty + 16) * 8 + ct] = zsq[1];
            }
        }
        grid.sync();
        // F phase: LN + tanh, write h into ring slot s&1 (+ h2 for layer 2)
        {
            const int gid = blk * NTHR + tid;   // 65536 threads == B*H
            #pragma unroll
            for (int uu = 0; uu < 6; ++uu) {
                const int ll = uu % 3, dd = uu / 3;
                const int tt = s - ll;
                if (tt < 0 || tt >= Tdim) continue;
                const int b = gid >> 9, h = gid & 511;
                float sm = 0.f, sq = 0.f;
                #pragma unroll
                for (int c = 0; c < 8; ++c) {
                    sm += a.ps[(uu * Bdim + b) * 8 + c];
                    sq += a.pq[(uu * Bdim + b) * 8 + c];
                }
                float m = sm * (1.0f / Hdim);
                float var = sq * (1.0f / Hdim) - m * m;
                float rstd = rsqrtf(var + LNEPS);
                float z = a.zb[(uu * Bdim + b) * Hdim + h];
                float hv = fast_tanh((z - m) * rstd * a.lng[ll * Hdim + h]
                                     + a.lnb[ll * Hdim + h]);
                a.hs[((dd * 3 + ll) * 2 + (s & 1)) * (Bdim * Hdim) + gid] = hv;
                if (ll == 2)
                    a.h2[(dd * Tdim + tt) * (Bdim * Hdim) + gid] = hv;
            }
        }
        grid.sync();
    }
}

// FC with r2l pad-gather fused into staging. 64 rows (same batch b) per block.
__global__ __launch_bounds__(NTHR) void fc_kernel(
    const float* __restrict__ h2, const int* __restrict__ pad,
    const float* __restrict__ Wfc, const float* __restrict__ bfc,
    float* __restrict__ out)
{
    __shared__ float sA[64 * 68];
    __shared__ float sB[64 * 48];
    const int blk = blockIdx.x, tid = threadIdx.x;
    const int b = blk >> 2;
    const int j0 = (blk & 3) * 64;
    const int p = pad[b];
    const int rg = tid >> 4;        // 0..15 -> rows rg*4..rg*4+3
    const int c0 = (tid & 15) * 3;  // cols c0..c0+2 (48-padded)
    float acc[4][3] = {};

    for (int k0 = 0; k0 < 2 * Hdim; k0 += 64) {
        {   // stage A: 64 rows x 64 k (with r2l gather)
            int rr = tid >> 2;
            int kp = (tid & 3) * 16;
            int j = j0 + rr;
            const float* src;
            if (k0 < Hdim) {
                src = h2 + ((0 * Tdim + j) * Bdim + b) * Hdim + k0 + kp;
            } else {
                int idx = (j < p) ? (p - j - 1) : j;
                src = h2 + ((1 * Tdim + idx) * Bdim + b) * Hdim + (k0 - Hdim) + kp;
            }
            #pragma unroll
            for (int i = 0; i < 4; ++i) {
                float4 v = *(const float4*)(src + i * 4);
                *(float4*)&sA[rr * 68 + kp + i * 4] = v;
            }
        }
        // stage B: W_fc[k0..k0+63][0..44] -> 48-padded
        for (int e = tid; e < 64 * 48; e += NTHR) {
            int kk = e / 48, c = e - kk * 48;
            sB[e] = (c < NC) ? Wfc[(k0 + kk) * NC + c] : 0.f;
        }
        __syncthreads();
        for (int kk = 0; kk < 64; ++kk) {
            float b0 = sB[kk * 48 + c0 + 0];
            float b1 = sB[kk * 48 + c0 + 1];
            float b2 = sB[kk * 48 + c0 + 2];
            #pragma unroll
            for (int i = 0; i < 4; ++i) {
                float av = sA[(rg * 4 + i) * 68 + kk];
                acc[i][0] += av * b0; acc[i][1] += av * b1; acc[i][2] += av * b2;
            }
        }
        __syncthreads();
    }
    #pragma unroll
    for (int i = 0; i < 4; ++i) {
        int r = blk * 64 + rg * 4 + i;
        #pragma unroll
        for (int jj = 0; jj < 3; ++jj) {
            int c = c0 + jj;
            if (c < NC) out[r * NC + c] = acc[i][jj] + bfc[c];
        }
    }
}

extern "C" void kernel_launch(void* const* d_in, const int* in_sizes, int n_in,
                              void* d_out, int out_size, void* d_ws, size_t ws_size,
                              hipStream_t stream) {
    const float* x      = (const float*)d_in[0];
    const float* rx     = (const float*)d_in[1];
    const int*   pad    = (const int*)d_in[2];
    const float* Wemb   = (const float*)d_in[4];
    const float* bemb   = (const float*)d_in[5];
    const float* Wx_l2r = (const float*)d_in[6];
    const float* bx_l2r = (const float*)d_in[7];
    const float* Wh_l2r = (const float*)d_in[8];
    const float* bh_l2r = (const float*)d_in[9];
    const float* Wx_r2l = (const float*)d_in[10];
    const float* bx_r2l = (const float*)d_in[11];
    const float* Wh_r2l = (const float*)d_in[12];
    const float* bh_r2l = (const float*)d_in[13];
    const float* lng    = (const float*)d_in[14];
    const float* lnb    = (const float*)d_in[15];
    const float* Wfc    = (const float*)d_in[16];
    const float* bfc    = (const float*)d_in[17];

    float* ws = (float*)d_ws;
    float* h2  = ws;                                    // 2*T*B*H
    float* hs  = h2  + 2 * Tdim * Bdim * Hdim;          // 2*3*2*B*H
    float* zb  = hs  + 2 * 3 * 2 * Bdim * Hdim;         // 6*B*H
    float* psx = zb  + 6 * Bdim * Hdim;                 // 6*B*8
    float* pqx = psx + 6 * Bdim * 8;                    // 6*B*8
    float* W0  = pqx + 6 * Bdim * 8;                    // 2*KX*H
    float* cbp = W0  + 2 * KXdim * Hdim;                // 2*3*H

    prep_kernel<<<(2 * KXdim * Hdim + 2 * 3 * Hdim) / NTHR, NTHR, 0, stream>>>(
        Wemb, bemb, Wx_l2r, bx_l2r, bh_l2r, Wx_r2l, bx_r2l, bh_r2l, W0, cbp);

    RnnArgs a;
    a.x0 = x; a.x1 = rx;
    a.Wx[0] = Wx_l2r; a.Wx[1] = Wx_r2l;
    a.Wh[0] = Wh_l2r; a.Wh[1] = Wh_r2l;
    a.lng = lng; a.lnb = lnb;
    a.W0 = W0; a.cb = cbp;
    a.h2 = h2; a.hs = hs; a.zb = zb; a.ps = psx; a.pq = pqx;
    void* kargs[] = { &a };
    hipLaunchCooperativeKernel((void*)rnn_coop, dim3(NBLK), dim3(NTHR),
                               kargs, 0, stream);

    fc_kernel<<<(Bdim * Tdim) / 64, NTHR, 0, stream>>>(h2, pad, Wfc, bfc, (float*)d_out);
}

// Round 2
// 27317.395 us; speedup vs baseline: 1.0266x; 1.0266x over previous
//
#include <hip/hip_runtime.h>

#define Bdim 128
#define Tdim 256
#define Hdim 512
#define INdim 300
#define KXdim 320
#define NC 45
#define NTHR 256

typedef _Float16 h16;
typedef __attribute__((ext_vector_type(8))) _Float16 half8;
typedef __attribute__((ext_vector_type(4))) float float4v;

__device__ __forceinline__ float fast_tanh(float v) {
    float e = __expf(2.0f * v);
    return 1.0f - 2.0f / (e + 1.0f);
}

// ---------------- prep1: W0 = Wemb @ Wx0 (fp32), cb fused biases ----------------
__global__ __launch_bounds__(NTHR) void prep1_kernel(
    const float* Wemb, const float* bemb,
    const float* Wx_l2r, const float* bx_l2r, const float* bh_l2r,
    const float* Wx_r2l, const float* bx_r2l, const float* bh_r2l,
    float* W0, float* cb)
{
    int gid = blockIdx.x * NTHR + threadIdx.x;
    const int nW0 = 2 * KXdim * Hdim;
    if (gid < nW0) {
        int dir = gid / (KXdim * Hdim);
        int rem = gid % (KXdim * Hdim);
        int i = rem / Hdim, h = rem % Hdim;
        const float* Wx = dir ? Wx_r2l : Wx_l2r;
        float s = 0.f;
        if (i < INdim) {
            for (int k = 0; k < Hdim; ++k)
                s += Wemb[i * Hdim + k] * Wx[k * Hdim + h];
        }
        W0[gid] = s;
    } else {
        int idx = gid - nW0;
        if (idx < 2 * 3 * Hdim) {
            int dir = idx / (3 * Hdim);
            int l = (idx / Hdim) % 3;
            int h = idx % Hdim;
            const float* Wx = dir ? Wx_r2l : Wx_l2r;
            const float* bx = dir ? bx_r2l : bx_l2r;
            const float* bh = dir ? bh_r2l : bh_l2r;
            float s = bx[l * Hdim + h] + bh[l * Hdim + h];
            if (l == 0) {
                for (int k = 0; k < Hdim; ++k)
                    s += bemb[k] * Wx[k * Hdim + h];
            }
            cb[idx] = s;
        }
    }
}

// ---------------- pack_W: fp16 B-fragment layout [u][cs16][ks32][nt2][lane64][j8] ----
__global__ __launch_bounds__(NTHR) void pack_W_kernel(
    const float* W0,
    const float* Wx_l2r, const float* Wh_l2r,
    const float* Wx_r2l, const float* Wh_r2l,
    h16* Wfrag)
{
    int e = blockIdx.x * NTHR + threadIdx.x;
    if (e >= 6 * 16 * 32 * 2 * 64 * 8) return;
    int j    = e & 7;
    int lane = (e >> 3) & 63;
    int nt   = (e >> 9) & 1;
    int ks   = (e >> 10) & 31;
    int cs   = (e >> 15) & 15;
    int u    = e >> 19;
    int dir = u / 3, l = u % 3;
    int n  = cs * 32 + nt * 16 + (lane & 15);
    int kk = ks * 32 + ((lane >> 4) * 8) + j;
    float v;
    if (kk < 512) {
        if (l == 0) {
            v = (kk < KXdim) ? W0[(dir * KXdim + kk) * Hdim + n] : 0.f;
        } else {
            const float* Wx = dir ? Wx_r2l : Wx_l2r;
            v = Wx[(l * Hdim + kk) * Hdim + n];
        }
    } else {
        const float* Wh = dir ? Wh_r2l : Wh_l2r;
        v = Wh[(l * Hdim + (kk - 512)) * Hdim + n];
    }
    Wfrag[e] = (h16)v;
}

// ---------------- pack_W0f: fp16 B-frags of W0 for zx0 kernel --------------------
__global__ __launch_bounds__(NTHR) void pack_W0f_kernel(const float* W0, h16* W0f)
{
    int e = blockIdx.x * NTHR + threadIdx.x;
    if (e >= 2 * 32 * 10 * 64 * 8) return;
    int j    = e & 7;
    int lane = (e >> 3) & 63;
    int rest = e >> 9;          // dir*32*10 + nt*10 + ks
    int ks   = rest % 10;
    rest /= 10;
    int nt   = rest & 31;
    int dir  = rest >> 5;
    int k = ks * 32 + ((lane >> 4) * 8) + j;   // < 320
    int n = nt * 16 + (lane & 15);
    W0f[e] = (h16)W0[(dir * KXdim + k) * Hdim + n];
}

// ---------------- zx0: zx0f[dir][t][nt32][mt8][lane64][reg4] fp16 ----------------
__global__ __launch_bounds__(NTHR) void zx0_kernel(
    const float* __restrict__ x0, const float* __restrict__ x1,
    const h16* __restrict__ W0f, const float* __restrict__ cb,
    h16* __restrict__ zx0f)
{
    int bx = blockIdx.x;
    int t = bx & 255, mh = (bx >> 8) & 1, dir = bx >> 9;
    const int tid = threadIdx.x;
    __shared__ h16 xl[64 * 328];
    const float* xs = dir ? x1 : x0;
    for (int i = tid; i < 64 * 328; i += NTHR) {
        int r = i / 328, k = i - r * 328;
        int b = mh * 64 + r;
        float v = (k < INdim) ? xs[(b * Tdim + t) * INdim + k] : 0.f;
        xl[i] = (h16)v;
    }
    __syncthreads();
    int wave = tid >> 6, lane = tid & 63;
    int r15 = lane & 15, q = lane >> 4;
    for (int nt = 0; nt < 32; ++nt) {
        float4v acc = {0.f, 0.f, 0.f, 0.f};
        #pragma unroll
        for (int ks = 0; ks < 10; ++ks) {
            half8 af = *(const half8*)&xl[(wave * 16 + r15) * 328 + ks * 32 + q * 8];
            half8 bf = *(const half8*)&W0f[(((dir * 32 + nt) * 10 + ks) * 64 + lane) * 8];
            acc = __builtin_amdgcn_mfma_f32_16x16x32_f16(af, bf, acc, 0, 0, 0);
        }
        int col = nt * 16 + r15;
        float cbv = cb[(dir * 3 + 0) * Hdim + col];
        union { h16 h[4]; uint2 u2; } o;
        #pragma unroll
        for (int r = 0; r < 4; ++r) o.h[r] = (h16)(acc[r] + cbv);
        h16* dst = zx0f + (((( (size_t)dir * Tdim + t) * 32 + nt) * 8 + (mh * 4 + wave)) * 64 + lane) * 4;
        *(uint2*)dst = o.u2;
    }
}

// ---------------- zeroinit: flags + hfrag slot 3 ---------------------------------
__global__ __launch_bounds__(NTHR) void zeroinit_kernel(uint4* hfrag16, int* flags)
{
    int gid = blockIdx.x * NTHR + threadIdx.x;
    // 6 units * slot3 * 65536 halves = 6 * 8192 uint4
    if (gid < 6 * 8192) {
        int u = gid >> 13, i = gid & 8191;
        hfrag16[(size_t)(u * 4 + 3) * 8192 + i] = make_uint4(0, 0, 0, 0);
    }
    if (gid < 16) flags[gid] = 0;
}

// ---------------- main persistent pipeline kernel --------------------------------
struct PipeArgs {
    const h16* Wfrag;    // [6][16][32][2][64][8]
    const h16* zx0f;     // [2][T][32][8][64][4]
    const float* cb;     // [2][3][H]
    const float* lng;    // [3][H]
    const float* lnb;    // [3][H]
    h16* hfrag;          // [6][4][16][8][64][8]
    h16* h2;             // [2][T][B][H]
    float* zbuf;         // [6][B][H]
    float* psum;         // [6][B][16]
    float* psq;          // [6][B][16]
    int* zflag;          // [8]
    int* hflag;          // [8]
};

__global__ __launch_bounds__(NTHR, 1) void rnn_pipe(PipeArgs a)
{
    const int blk = blockIdx.x, tid = threadIdx.x;
    const int u = blk & 7;
    if (u >= 6) return;                    // 64 idle blocks exit
    const int widx = blk >> 3;             // 0..31
    const int mtblk = widx & 1, cs = widx >> 1;
    const int dir = u / 3, l = u % 3;
    const int wave = tid >> 6, lane = tid & 63;
    const int gmt = mtblk * 4 + wave;      // global m-tile 0..7
    const int r15 = lane & 15, quad = lane >> 4;

    __shared__ h16 wlds[32768];            // 64 KB: [ks32][nt2][lane64][8]
    {
        const h16* src = a.Wfrag + (size_t)(u * 16 + cs) * 32768;
        for (int i = tid * 8; i < 32768; i += NTHR * 8)
            *(uint4*)&wlds[i] = *(const uint4*)&src[i];
    }
    __syncthreads();

    const int colbase = cs * 32 + r15;
    const float cb0v = (l > 0) ? a.cb[(dir * 3 + l) * Hdim + colbase] : 0.f;
    const float cb1v = (l > 0) ? a.cb[(dir * 3 + l) * Hdim + colbase + 16] : 0.f;

    for (int t = 0; t < Tdim; ++t) {
        // ---------------- G phase ----------------
        if (tid == 0) {
            if (t > 0)
                while (__hip_atomic_load(&a.hflag[u], __ATOMIC_RELAXED,
                                         __HIP_MEMORY_SCOPE_AGENT) < 32 * t)
                    __builtin_amdgcn_s_sleep(1);
            if (l > 0)
                while (__hip_atomic_load(&a.hflag[u - 1], __ATOMIC_RELAXED,
                                         __HIP_MEMORY_SCOPE_AGENT) < 32 * (t + 1))
                    __builtin_amdgcn_s_sleep(1);
        }
        __syncthreads();
        __threadfence();   // acquire: invalidate L1 before reading hfrag

        float4v acc0, acc1;
        if (l == 0) {
            const h16* zp = a.zx0f +
                (((((size_t)dir * Tdim + t) * 32 + cs * 2) * 8 + gmt) * 64 + lane) * 4;
            acc0[0] = (float)zp[0]; acc0[1] = (float)zp[1];
            acc0[2] = (float)zp[2]; acc0[3] = (float)zp[3];
            const h16* zp1 = zp + 2048;
            acc1[0] = (float)zp1[0]; acc1[1] = (float)zp1[1];
            acc1[2] = (float)zp1[2]; acc1[3] = (float)zp1[3];
        } else {
            acc0 = (float4v){0.f, 0.f, 0.f, 0.f};
            acc1 = (float4v){0.f, 0.f, 0.f, 0.f};
        }

        const h16* basePrev = a.hfrag + (size_t)(u * 4 + ((t - 1) & 3)) * 65536;
        if (l > 0) {
            const h16* baseLow = a.hfrag + (size_t)((u - 1) * 4 + (t & 3)) * 65536;
            #pragma unroll 8
            for (int ksl = 0; ksl < 16; ++ksl) {
                half8 af = *(const half8*)&baseLow[((ksl * 8 + gmt) * 64 + lane) * 8];
                half8 b0 = *(const half8*)&wlds[((ksl * 2 + 0) * 64 + lane) * 8];
                half8 b1 = *(const half8*)&wlds[((ksl * 2 + 1) * 64 + lane) * 8];
                acc0 = __builtin_amdgcn_mfma_f32_16x16x32_f16(af, b0, acc0, 0, 0, 0);
                acc1 = __builtin_amdgcn_mfma_f32_16x16x32_f16(af, b1, acc1, 0, 0, 0);
            }
        }
        #pragma unroll 8
        for (int ksl = 0; ksl < 16; ++ksl) {
            half8 af = *(const half8*)&basePrev[((ksl * 8 + gmt) * 64 + lane) * 8];
            half8 b0 = *(const half8*)&wlds[(((ksl + 16) * 2 + 0) * 64 + lane) * 8];
            half8 b1 = *(const half8*)&wlds[(((ksl + 16) * 2 + 1) * 64 + lane) * 8];
            acc0 = __builtin_amdgcn_mfma_f32_16x16x32_f16(af, b0, acc0, 0, 0, 0);
            acc1 = __builtin_amdgcn_mfma_f32_16x16x32_f16(af, b1, acc1, 0, 0, 0);
        }

        // epilogue: bias, z store, per-row partial stats
        #pragma unroll
        for (int r = 0; r < 4; ++r) {
            float z0 = acc0[r] + cb0v;
            float z1 = acc1[r] + cb1v;
            int b = mtblk * 64 + wave * 16 + quad * 4 + r;
            a.zbuf[(u * Bdim + b) * Hdim + colbase]      = z0;
            a.zbuf[(u * Bdim + b) * Hdim + colbase + 16] = z1;
            float s = z0 + z1, q = z0 * z0 + z1 * z1;
            s += __shfl_xor(s, 1);  q += __shfl_xor(q, 1);
            s += __shfl_xor(s, 2);  q += __shfl_xor(q, 2);
            s += __shfl_xor(s, 4);  q += __shfl_xor(q, 4);
            s += __shfl_xor(s, 8);  q += __shfl_xor(q, 8);
            if (r15 == 0) {
                a.psum[(u * Bdim + b) * 16 + cs] = s;
                a.psq [(u * Bdim + b) * 16 + cs] = q;
            }
        }
        __threadfence();
        __syncthreads();
        if (tid == 0)
            __hip_atomic_fetch_add(&a.zflag[u], 1, __ATOMIC_RELEASE,
                                   __HIP_MEMORY_SCOPE_AGENT);

        // ---------------- F phase ----------------
        if (tid == 0) {
            while (__hip_atomic_load(&a.zflag[u], __ATOMIC_RELAXED,
                                     __HIP_MEMORY_SCOPE_AGENT) < 32 * (t + 1))
                __builtin_amdgcn_s_sleep(1);
            if (l < 2 && t >= 4)   // ring-depth-4 overwrite throttle
                while (__hip_atomic_load(&a.zflag[u + 1], __ATOMIC_RELAXED,
                                         __HIP_MEMORY_SCOPE_AGENT) < 32 * (t - 3))
                    __builtin_amdgcn_s_sleep(1);
        }
        __syncthreads();
        __threadfence();

        {
            int flat = widx * 2048 + tid * 8;      // covers B*H
            int b = flat >> 9, hc = flat & 511;
            float sm = 0.f, sq = 0.f;
            #pragma unroll
            for (int c = 0; c < 16; ++c) {
                sm += a.psum[(u * Bdim + b) * 16 + c];
                sq += a.psq [(u * Bdim + b) * 16 + c];
            }
            float m = sm * (1.0f / Hdim);
            float var = sq * (1.0f / Hdim) - m * m;
            float rstd = rsqrtf(var + 1e-5f);
            union { h16 h[8]; uint4 u4; } o;
            #pragma unroll
            for (int j = 0; j < 8; ++j) {
                float z = a.zbuf[(u * Bdim + b) * Hdim + hc + j];
                float g = a.lng[l * Hdim + hc + j];
                float bb = a.lnb[l * Hdim + hc + j];
                o.h[j] = (h16)fast_tanh((z - m) * rstd * g + bb);
            }
            int ksF = hc >> 5;
            int lane2 = (b & 15) | (((hc >> 3) & 3) << 4);
            h16* dst = a.hfrag + (size_t)(u * 4 + (t & 3)) * 65536 +
                       ((ksF * 8 + (b >> 4)) * 64 + lane2) * 8;
            *(uint4*)dst = o.u4;
            if (l == 2) {
                h16* d2 = a.h2 + (((size_t)dir * Tdim + t) * Bdim + b) * Hdim + hc;
                *(uint4*)d2 = o.u4;
            }
        }
        __threadfence();
        __syncthreads();
        if (tid == 0)
            __hip_atomic_fetch_add(&a.hflag[u], 1, __ATOMIC_RELEASE,
                                   __HIP_MEMORY_SCOPE_AGENT);
    }
}

// ---------------- FC: logits = [h_l2r ; gather(h_r2l)] @ W_fc + b_fc -------------
__global__ __launch_bounds__(NTHR) void fc_kernel(
    const h16* __restrict__ h2, const int* __restrict__ pad,
    const float* __restrict__ Wfc, const float* __restrict__ bfc,
    float* __restrict__ out)
{
    __shared__ float sA[64 * 68];
    __shared__ float sB[64 * 48];
    const int blk = blockIdx.x, tid = threadIdx.x;
    const int b = blk >> 2;
    const int j0 = (blk & 3) * 64;
    const int p = pad[b];
    const int rg = tid >> 4;
    const int c0 = (tid & 15) * 3;
    float acc[4][3] = {};

    for (int k0 = 0; k0 < 2 * Hdim; k0 += 64) {
        {
            int rr = tid >> 2;
            int kp = (tid & 3) * 16;
            int j = j0 + rr;
            const h16* src;
            if (k0 < Hdim) {
                src = h2 + (((size_t)0 * Tdim + j) * Bdim + b) * Hdim + k0 + kp;
            } else {
                int idx = (j < p) ? (p - j - 1) : j;
                src = h2 + (((size_t)1 * Tdim + idx) * Bdim + b) * Hdim + (k0 - Hdim) + kp;
            }
            union { uint4 u4; h16 h[8]; } w0, w1;
            w0.u4 = *(const uint4*)src;
            w1.u4 = *(const uint4*)(src + 8);
            #pragma unroll
            for (int i = 0; i < 8; ++i) {
                sA[rr * 68 + kp + i]     = (float)w0.h[i];
                sA[rr * 68 + kp + 8 + i] = (float)w1.h[i];
            }
        }
        for (int e = tid; e < 64 * 48; e += NTHR) {
            int kk = e / 48, c = e - kk * 48;
            sB[e] = (c < NC) ? Wfc[(k0 + kk) * NC + c] : 0.f;
        }
        __syncthreads();
        for (int kk = 0; kk < 64; ++kk) {
            float b0 = sB[kk * 48 + c0 + 0];
            float b1 = sB[kk * 48 + c0 + 1];
            float b2 = sB[kk * 48 + c0 + 2];
            #pragma unroll
            for (int i = 0; i < 4; ++i) {
                float av = sA[(rg * 4 + i) * 68 + kk];
                acc[i][0] += av * b0; acc[i][1] += av * b1; acc[i][2] += av * b2;
            }
        }
        __syncthreads();
    }
    #pragma unroll
    for (int i = 0; i < 4; ++i) {
        int r = blk * 64 + rg * 4 + i;
        #pragma unroll
        for (int jj = 0; jj < 3; ++jj) {
            int c = c0 + jj;
            if (c < NC) out[r * NC + c] = acc[i][jj] + bfc[c];
        }
    }
}

extern "C" void kernel_launch(void* const* d_in, const int* in_sizes, int n_in,
                              void* d_out, int out_size, void* d_ws, size_t ws_size,
                              hipStream_t stream) {
    const float* x      = (const float*)d_in[0];
    const float* rx     = (const float*)d_in[1];
    const int*   pad    = (const int*)d_in[2];
    const float* Wemb   = (const float*)d_in[4];
    const float* bemb   = (const float*)d_in[5];
    const float* Wx_l2r = (const float*)d_in[6];
    const float* bx_l2r = (const float*)d_in[7];
    const float* Wh_l2r = (const float*)d_in[8];
    const float* bh_l2r = (const float*)d_in[9];
    const float* Wx_r2l = (const float*)d_in[10];
    const float* bx_r2l = (const float*)d_in[11];
    const float* Wh_r2l = (const float*)d_in[12];
    const float* bh_r2l = (const float*)d_in[13];
    const float* lng    = (const float*)d_in[14];
    const float* lnb    = (const float*)d_in[15];
    const float* Wfc    = (const float*)d_in[16];
    const float* bfc    = (const float*)d_in[17];

    char* base = (char*)d_ws;
    size_t off = 0;
    auto alloc = [&](size_t bytes) { char* p = base + off; off += (bytes + 255) & ~(size_t)255; return p; };
    h16*   zx0f  = (h16*)  alloc((size_t)2 * Tdim * 32 * 8 * 64 * 4 * 2);      // 67 MB
    h16*   h2    = (h16*)  alloc((size_t)2 * Tdim * Bdim * Hdim * 2);          // 67 MB
    h16*   Wfrag = (h16*)  alloc((size_t)6 * 16 * 32768 * 2);                  // 6 MB
    h16*   W0f   = (h16*)  alloc((size_t)2 * 32 * 10 * 64 * 8 * 2);            // 0.65 MB
    h16*   hfrag = (h16*)  alloc((size_t)6 * 4 * 65536 * 2);                   // 3 MB
    float* zbuf  = (float*)alloc((size_t)6 * Bdim * Hdim * 4);                 // 1.5 MB
    float* psum  = (float*)alloc((size_t)6 * Bdim * 16 * 4);
    float* psq   = (float*)alloc((size_t)6 * Bdim * 16 * 4);
    float* W0    = (float*)alloc((size_t)2 * KXdim * Hdim * 4);                // 1.3 MB
    float* cb    = (float*)alloc((size_t)2 * 3 * Hdim * 4);
    int*   flags = (int*)  alloc(64);
    int* zflag = flags;
    int* hflag = flags + 8;

    prep1_kernel<<<(2 * KXdim * Hdim + 2 * 3 * Hdim) / NTHR, NTHR, 0, stream>>>(
        Wemb, bemb, Wx_l2r, bx_l2r, bh_l2r, Wx_r2l, bx_r2l, bh_r2l, W0, cb);

    pack_W_kernel<<<(6 * 16 * 32 * 2 * 64 * 8) / NTHR, NTHR, 0, stream>>>(
        W0, Wx_l2r, Wh_l2r, Wx_r2l, Wh_r2l, Wfrag);

    pack_W0f_kernel<<<(2 * 32 * 10 * 64 * 8) / NTHR, NTHR, 0, stream>>>(W0, W0f);

    zx0_kernel<<<1024, NTHR, 0, stream>>>(x, rx, W0f, cb, zx0f);

    zeroinit_kernel<<<(6 * 8192 + NTHR - 1) / NTHR, NTHR, 0, stream>>>(
        (uint4*)hfrag, flags);

    PipeArgs a;
    a.Wfrag = Wfrag; a.zx0f = zx0f; a.cb = cb; a.lng = lng; a.lnb = lnb;
    a.hfrag = hfrag; a.h2 = h2; a.zbuf = zbuf; a.psum = psum; a.psq = psq;
    a.zflag = zflag; a.hflag = hflag;
    void* kargs[] = { &a };
    hipLaunchCooperativeKernel((void*)rnn_pipe, dim3(NTHR), dim3(NTHR), kargs, 0, stream);

    fc_kernel<<<(Bdim * Tdim) / 64, NTHR, 0, stream>>>(h2, pad, Wfc, bfc, (float*)d_out);
}

// Round 3
// 4445.160 us; speedup vs baseline: 6.3089x; 6.1454x over previous
//
#include <hip/hip_runtime.h>

#define Bdim 128
#define Tdim 256
#define Hdim 512
#define INdim 300
#define KXdim 320
#define NC 45
#define NTHR 256

typedef _Float16 h16;
typedef __attribute__((ext_vector_type(8))) _Float16 half8;
typedef __attribute__((ext_vector_type(4))) float float4v;

__device__ __forceinline__ float fast_tanh(float v) {
    float e = __expf(2.0f * v);
    return 1.0f - 2.0f / (e + 1.0f);
}

// ---- coherence-point (sc0 sc1) access helpers: relaxed agent-scope atomics ----
__device__ __forceinline__ int ld_flag(const int* p) {
    return __hip_atomic_load((int*)p, __ATOMIC_RELAXED, __HIP_MEMORY_SCOPE_AGENT);
}
__device__ __forceinline__ void st_flag(int* p, int v) {
    __hip_atomic_store(p, v, __ATOMIC_RELAXED, __HIP_MEMORY_SCOPE_AGENT);
}
__device__ __forceinline__ float ld_f32c(const float* p) {
    return __hip_atomic_load((float*)p, __ATOMIC_RELAXED, __HIP_MEMORY_SCOPE_AGENT);
}
__device__ __forceinline__ void st_f32c(float* p, float v) {
    __hip_atomic_store(p, v, __ATOMIC_RELAXED, __HIP_MEMORY_SCOPE_AGENT);
}
__device__ __forceinline__ half8 ld8c(const h16* p) {
    union { uint u[4]; half8 h; } r;
    const uint* q = (const uint*)p;
    r.u[0] = __hip_atomic_load((uint*)(q + 0), __ATOMIC_RELAXED, __HIP_MEMORY_SCOPE_AGENT);
    r.u[1] = __hip_atomic_load((uint*)(q + 1), __ATOMIC_RELAXED, __HIP_MEMORY_SCOPE_AGENT);
    r.u[2] = __hip_atomic_load((uint*)(q + 2), __ATOMIC_RELAXED, __HIP_MEMORY_SCOPE_AGENT);
    r.u[3] = __hip_atomic_load((uint*)(q + 3), __ATOMIC_RELAXED, __HIP_MEMORY_SCOPE_AGENT);
    return r.h;
}
__device__ __forceinline__ void st8c(h16* p, const uint* u) {
    uint* q = (uint*)p;
    __hip_atomic_store(q + 0, u[0], __ATOMIC_RELAXED, __HIP_MEMORY_SCOPE_AGENT);
    __hip_atomic_store(q + 1, u[1], __ATOMIC_RELAXED, __HIP_MEMORY_SCOPE_AGENT);
    __hip_atomic_store(q + 2, u[2], __ATOMIC_RELAXED, __HIP_MEMORY_SCOPE_AGENT);
    __hip_atomic_store(q + 3, u[3], __ATOMIC_RELAXED, __HIP_MEMORY_SCOPE_AGENT);
}

// ---------------- prep1: W0 = Wemb @ Wx0 (fp32), cb fused biases ----------------
__global__ __launch_bounds__(NTHR) void prep1_kernel(
    const float* Wemb, const float* bemb,
    const float* Wx_l2r, const float* bx_l2r, const float* bh_l2r,
    const float* Wx_r2l, const float* bx_r2l, const float* bh_r2l,
    float* W0, float* cb)
{
    int gid = blockIdx.x * NTHR + threadIdx.x;
    const int nW0 = 2 * KXdim * Hdim;
    if (gid < nW0) {
        int dir = gid / (KXdim * Hdim);
        int rem = gid % (KXdim * Hdim);
        int i = rem / Hdim, h = rem % Hdim;
        const float* Wx = dir ? Wx_r2l : Wx_l2r;
        float s = 0.f;
        if (i < INdim) {
            for (int k = 0; k < Hdim; ++k)
                s += Wemb[i * Hdim + k] * Wx[k * Hdim + h];
        }
        W0[gid] = s;
    } else {
        int idx = gid - nW0;
        if (idx < 2 * 3 * Hdim) {
            int dir = idx / (3 * Hdim);
            int l = (idx / Hdim) % 3;
            int h = idx % Hdim;
            const float* Wx = dir ? Wx_r2l : Wx_l2r;
            const float* bx = dir ? bx_r2l : bx_l2r;
            const float* bh = dir ? bh_r2l : bh_l2r;
            float s = bx[l * Hdim + h] + bh[l * Hdim + h];
            if (l == 0) {
                for (int k = 0; k < Hdim; ++k)
                    s += bemb[k] * Wx[k * Hdim + h];
            }
            cb[idx] = s;
        }
    }
}

// ---------------- pack_W: fp16 B-fragment layout [u][cs16][ks32][nt2][lane64][j8] ----
__global__ __launch_bounds__(NTHR) void pack_W_kernel(
    const float* W0,
    const float* Wx_l2r, const float* Wh_l2r,
    const float* Wx_r2l, const float* Wh_r2l,
    h16* Wfrag)
{
    int e = blockIdx.x * NTHR + threadIdx.x;
    if (e >= 6 * 16 * 32 * 2 * 64 * 8) return;
    int j    = e & 7;
    int lane = (e >> 3) & 63;
    int nt   = (e >> 9) & 1;
    int ks   = (e >> 10) & 31;
    int cs   = (e >> 15) & 15;
    int u    = e >> 19;
    int dir = u / 3, l = u % 3;
    int n  = cs * 32 + nt * 16 + (lane & 15);
    int kk = ks * 32 + ((lane >> 4) * 8) + j;
    float v;
    if (kk < 512) {
        if (l == 0) {
            v = (kk < KXdim) ? W0[(dir * KXdim + kk) * Hdim + n] : 0.f;
        } else {
            const float* Wx = dir ? Wx_r2l : Wx_l2r;
            v = Wx[(l * Hdim + kk) * Hdim + n];
        }
    } else {
        const float* Wh = dir ? Wh_r2l : Wh_l2r;
        v = Wh[(l * Hdim + (kk - 512)) * Hdim + n];
    }
    Wfrag[e] = (h16)v;
}

// ---------------- pack_W0f: fp16 B-frags of W0 for zx0 kernel --------------------
__global__ __launch_bounds__(NTHR) void pack_W0f_kernel(const float* W0, h16* W0f)
{
    int e = blockIdx.x * NTHR + threadIdx.x;
    if (e >= 2 * 32 * 10 * 64 * 8) return;
    int j    = e & 7;
    int lane = (e >> 3) & 63;
    int rest = e >> 9;
    int ks   = rest % 10;
    rest /= 10;
    int nt   = rest & 31;
    int dir  = rest >> 5;
    int k = ks * 32 + ((lane >> 4) * 8) + j;
    int n = nt * 16 + (lane & 15);
    W0f[e] = (h16)W0[(dir * KXdim + k) * Hdim + n];
}

// ---------------- zx0: zx0f[dir][t][nt32][mt8][lane64][reg4] fp16 ----------------
__global__ __launch_bounds__(NTHR) void zx0_kernel(
    const float* __restrict__ x0, const float* __restrict__ x1,
    const h16* __restrict__ W0f, const float* __restrict__ cb,
    h16* __restrict__ zx0f)
{
    int bx = blockIdx.x;
    int t = bx & 255, mh = (bx >> 8) & 1, dir = bx >> 9;
    const int tid = threadIdx.x;
    __shared__ h16 xl[64 * 328];
    const float* xs = dir ? x1 : x0;
    for (int i = tid; i < 64 * 328; i += NTHR) {
        int r = i / 328, k = i - r * 328;
        int b = mh * 64 + r;
        float v = (k < INdim) ? xs[(b * Tdim + t) * INdim + k] : 0.f;
        xl[i] = (h16)v;
    }
    __syncthreads();
    int wave = tid >> 6, lane = tid & 63;
    int r15 = lane & 15, q = lane >> 4;
    for (int nt = 0; nt < 32; ++nt) {
        float4v acc = {0.f, 0.f, 0.f, 0.f};
        #pragma unroll
        for (int ks = 0; ks < 10; ++ks) {
            half8 af = *(const half8*)&xl[(wave * 16 + r15) * 328 + ks * 32 + q * 8];
            half8 bf = *(const half8*)&W0f[(((dir * 32 + nt) * 10 + ks) * 64 + lane) * 8];
            acc = __builtin_amdgcn_mfma_f32_16x16x32_f16(af, bf, acc, 0, 0, 0);
        }
        int col = nt * 16 + r15;
        float cbv = cb[(dir * 3 + 0) * Hdim + col];
        union { h16 h[4]; uint2 u2; } o;
        #pragma unroll
        for (int r = 0; r < 4; ++r) o.h[r] = (h16)(acc[r] + cbv);
        h16* dst = zx0f + (((( (size_t)dir * Tdim + t) * 32 + nt) * 8 + (mh * 4 + wave)) * 64 + lane) * 4;
        *(uint2*)dst = o.u2;
    }
}

// ---------------- zeroinit: flags + hfrag slot 3 ---------------------------------
__global__ __launch_bounds__(NTHR) void zeroinit_kernel(uint4* hfrag4, int* zdone, int* hdone)
{
    int gid = blockIdx.x * NTHR + threadIdx.x;
    if (gid < 6 * 8192) {
        int u = gid >> 13, i = gid & 8191;
        hfrag4[(size_t)(u * 4 + 3) * 8192 + i] = make_uint4(0, 0, 0, 0);
    }
    if (gid < 6 * 32) { zdone[gid] = 0; hdone[gid] = 0; }
}

// ---------------- main persistent pipeline kernel --------------------------------
struct PipeArgs {
    const h16* Wfrag;    // [6][16][32][2][64][8]
    const h16* zx0f;     // [2][T][32][8][64][4]
    const float* cb;     // [2][3][H]
    const float* lng;    // [3][H]
    const float* lnb;    // [3][H]
    h16* hfrag;          // [6][4][16][8][64][8]  (ring of 4 slots)
    h16* h2;             // [2][T][B][H]
    float* psum;         // [6][B][16]
    float* psq;          // [6][B][16]
    int* zdone;          // [6][32]  per-block G-complete stamp
    int* hdone;          // [6][32]  per-block LN-complete stamp
};

__global__ __launch_bounds__(NTHR, 1) void rnn_pipe(PipeArgs a)
{
    const int blk = blockIdx.x, tid = threadIdx.x;
    const int u = blk & 7;
    if (u >= 6) return;                    // idle blocks exit (no grid sync used)
    const int widx = blk >> 3;             // 0..31
    const int mtblk = widx & 1, cs = widx >> 1;
    const int dir = u / 3, l = u % 3;
    const int wave = tid >> 6, lane = tid & 63;
    const int gmt = mtblk * 4 + wave;      // m-tile 0..7
    const int r15 = lane & 15, quad = lane >> 4;

    __shared__ h16 wlds[16384];            // 32 KB: Wh frags [ks16][nt2][lane64][8]
    __shared__ float lds_ps[64 * 16];      // 4 KB
    __shared__ float lds_pq[64 * 16];      // 4 KB
    __shared__ h16 lds_z[64 * 32];         // 4 KB

    {   // stage Wh-half (ks 16..31) of this block's weight slab into LDS
        const h16* src = a.Wfrag + (size_t)(u * 16 + cs) * 32768 + 16384;
        for (int i = tid * 8; i < 16384; i += NTHR * 8)
            *(uint4*)&wlds[i] = *(const uint4*)&src[i];
    }
    __syncthreads();

    const h16* wxg = a.Wfrag + (size_t)(u * 16 + cs) * 32768;   // Wx frags (L2, plain)
    const int colbase = cs * 32 + r15;
    const float cb0v = (l > 0) ? a.cb[(dir * 3 + l) * Hdim + colbase] : 0.f;
    const float cb1v = (l > 0) ? a.cb[(dir * 3 + l) * Hdim + colbase + 16] : 0.f;
    const float g0  = a.lng[l * Hdim + colbase];
    const float g1  = a.lng[l * Hdim + colbase + 16];
    const float bb0 = a.lnb[l * Hdim + colbase];
    const float bb1 = a.lnb[l * Hdim + colbase + 16];

    for (int t = 0; t < Tdim; ++t) {
        // ---- combined pre-G wait: own LN(t-1), lower-layer LN(t), ring throttle ----
        for (;;) {
            int ok = 1;
            if (tid < 32) ok = (ld_flag(&a.hdone[u * 32 + tid]) >= t);
            else if (tid >= 64 && tid < 96) {
                if (l > 0) ok = (ld_flag(&a.hdone[(u - 1) * 32 + (tid - 64)]) >= t + 1);
            } else if (tid >= 128 && tid < 160) {
                if (l < 2 && t >= 4) ok = (ld_flag(&a.zdone[(u + 1) * 32 + (tid - 128)]) >= t - 3);
            }
            if (__syncthreads_and(ok)) break;
            __builtin_amdgcn_s_sleep(2);
        }

        // ---- G: z = h_low(t)@Wx + h_prev(t-1)@Wh (+ zx0 for l==0) ----
        float4v aL0 = {0.f,0.f,0.f,0.f}, aL1 = {0.f,0.f,0.f,0.f};
        float4v aP0, aP1;
        const h16* basePrev = a.hfrag + (size_t)(u * 4 + ((t + 3) & 3)) * 65536;
        if (l == 0) {
            const h16* zp = a.zx0f +
                (((((size_t)dir * Tdim + t) * 32 + cs * 2) * 8 + gmt) * 64 + lane) * 4;
            aP0[0] = (float)zp[0]; aP0[1] = (float)zp[1];
            aP0[2] = (float)zp[2]; aP0[3] = (float)zp[3];
            const h16* zp1 = zp + 2048;
            aP1[0] = (float)zp1[0]; aP1[1] = (float)zp1[1];
            aP1[2] = (float)zp1[2]; aP1[3] = (float)zp1[3];
            #pragma unroll 4
            for (int ksl = 0; ksl < 16; ++ksl) {
                half8 afP = ld8c(&basePrev[((ksl * 8 + gmt) * 64 + lane) * 8]);
                half8 bh0 = *(const half8*)&wlds[((ksl * 2 + 0) * 64 + lane) * 8];
                half8 bh1 = *(const half8*)&wlds[((ksl * 2 + 1) * 64 + lane) * 8];
                aP0 = __builtin_amdgcn_mfma_f32_16x16x32_f16(afP, bh0, aP0, 0, 0, 0);
                aP1 = __builtin_amdgcn_mfma_f32_16x16x32_f16(afP, bh1, aP1, 0, 0, 0);
            }
        } else {
            aP0 = (float4v){0.f,0.f,0.f,0.f};
            aP1 = (float4v){0.f,0.f,0.f,0.f};
            const h16* baseLow = a.hfrag + (size_t)((u - 1) * 4 + (t & 3)) * 65536;
            #pragma unroll 4
            for (int ksl = 0; ksl < 16; ++ksl) {
                half8 afL = ld8c(&baseLow[((ksl * 8 + gmt) * 64 + lane) * 8]);
                half8 afP = ld8c(&basePrev[((ksl * 8 + gmt) * 64 + lane) * 8]);
                half8 bx0 = *(const half8*)&wxg[((ksl * 2 + 0) * 64 + lane) * 8];
                half8 bx1 = *(const half8*)&wxg[((ksl * 2 + 1) * 64 + lane) * 8];
                half8 bh0 = *(const half8*)&wlds[((ksl * 2 + 0) * 64 + lane) * 8];
                half8 bh1 = *(const half8*)&wlds[((ksl * 2 + 1) * 64 + lane) * 8];
                aL0 = __builtin_amdgcn_mfma_f32_16x16x32_f16(afL, bx0, aL0, 0, 0, 0);
                aL1 = __builtin_amdgcn_mfma_f32_16x16x32_f16(afL, bx1, aL1, 0, 0, 0);
                aP0 = __builtin_amdgcn_mfma_f32_16x16x32_f16(afP, bh0, aP0, 0, 0, 0);
                aP1 = __builtin_amdgcn_mfma_f32_16x16x32_f16(afP, bh1, aP1, 0, 0, 0);
            }
        }

        // z in regs; partial LN stats -> psum (coherence-point stores)
        float z0[4], z1[4];
        #pragma unroll
        for (int r = 0; r < 4; ++r) {
            z0[r] = aL0[r] + aP0[r] + cb0v;
            z1[r] = aL1[r] + aP1[r] + cb1v;
            float s = z0[r] + z1[r];
            float q2 = z0[r] * z0[r] + z1[r] * z1[r];
            s += __shfl_xor(s, 1);  q2 += __shfl_xor(q2, 1);
            s += __shfl_xor(s, 2);  q2 += __shfl_xor(q2, 2);
            s += __shfl_xor(s, 4);  q2 += __shfl_xor(q2, 4);
            s += __shfl_xor(s, 8);  q2 += __shfl_xor(q2, 8);
            if (r15 == 0) {
                int b = mtblk * 64 + wave * 16 + quad * 4 + r;
                st_f32c(&a.psum[(u * Bdim + b) * 16 + cs], s);
                st_f32c(&a.psq [(u * Bdim + b) * 16 + cs], q2);
            }
        }
        __syncthreads();                    // drains vmcnt -> psum visible
        if (tid == 0) st_flag(&a.zdone[u * 32 + widx], t + 1);

        // ---- wait all unit blocks' psum for step t ----
        for (;;) {
            int ok = 1;
            if (tid < 32) ok = (ld_flag(&a.zdone[u * 32 + tid]) >= t + 1);
            if (__syncthreads_and(ok)) break;
            __builtin_amdgcn_s_sleep(2);
        }

        // ---- LN + tanh in place; pack via LDS transpose ----
        {   // stage this block's 64 rows of psum/psq
            int flat = tid * 4;
            int rl = flat >> 4, c = flat & 15;
            int b = mtblk * 64 + rl;
            #pragma unroll
            for (int j = 0; j < 4; ++j) {
                lds_ps[rl * 16 + c + j] = ld_f32c(&a.psum[(u * Bdim + b) * 16 + c + j]);
                lds_pq[rl * 16 + c + j] = ld_f32c(&a.psq [(u * Bdim + b) * 16 + c + j]);
            }
        }
        __syncthreads();
        #pragma unroll
        for (int r = 0; r < 4; ++r) {
            int rl = wave * 16 + quad * 4 + r;
            float sm = 0.f, sq = 0.f;
            #pragma unroll
            for (int c = 0; c < 16; ++c) { sm += lds_ps[rl * 16 + c]; sq += lds_pq[rl * 16 + c]; }
            float m = sm * (1.0f / Hdim);
            float var = sq * (1.0f / Hdim) - m * m;
            float rstd = rsqrtf(var + 1e-5f);
            lds_z[rl * 32 + r15]      = (h16)fast_tanh((z0[r] - m) * rstd * g0 + bb0);
            lds_z[rl * 32 + r15 + 16] = (h16)fast_tanh((z1[r] - m) * rstd * g1 + bb1);
        }
        __syncthreads();
        {   // packed octet store: hfrag (coherence point) + h2 (plain)
            int b_l = tid >> 2, c0 = (tid & 3) * 8;
            union { h16 h[8]; uint u4[4]; uint4 v; } o;
            #pragma unroll
            for (int j = 0; j < 8; ++j) o.h[j] = lds_z[b_l * 32 + c0 + j];
            int mt = mtblk * 4 + (b_l >> 4);
            int lane2 = (b_l & 15) | ((tid & 3) << 4);
            h16* dst = a.hfrag + (size_t)(u * 4 + (t & 3)) * 65536 +
                       ((size_t)((cs * 8 + mt) * 64 + lane2)) * 8;
            st8c(dst, o.u4);
            if (l == 2) {
                int b = mtblk * 64 + b_l;
                int h = cs * 32 + c0;
                *(uint4*)(a.h2 + (((size_t)dir * Tdim + t) * Bdim + b) * Hdim + h) = o.v;
            }
        }
        __syncthreads();                    // drains vmcnt -> hfrag visible
        if (tid == 0) st_flag(&a.hdone[u * 32 + widx], t + 1);
    }
}

// ---------------- FC: logits = [h_l2r ; gather(h_r2l)] @ W_fc + b_fc -------------
__global__ __launch_bounds__(NTHR) void fc_kernel(
    const h16* __restrict__ h2, const int* __restrict__ pad,
    const float* __restrict__ Wfc, const float* __restrict__ bfc,
    float* __restrict__ out)
{
    __shared__ float sA[64 * 68];
    __shared__ float sB[64 * 48];
    const int blk = blockIdx.x, tid = threadIdx.x;
    const int b = blk >> 2;
    const int j0 = (blk & 3) * 64;
    const int p = pad[b];
    const int rg = tid >> 4;
    const int c0 = (tid & 15) * 3;
    float acc[4][3] = {};

    for (int k0 = 0; k0 < 2 * Hdim; k0 += 64) {
        {
            int rr = tid >> 2;
            int kp = (tid & 3) * 16;
            int j = j0 + rr;
            const h16* src;
            if (k0 < Hdim) {
                src = h2 + (((size_t)0 * Tdim + j) * Bdim + b) * Hdim + k0 + kp;
            } else {
                int idx = (j < p) ? (p - j - 1) : j;
                src = h2 + (((size_t)1 * Tdim + idx) * Bdim + b) * Hdim + (k0 - Hdim) + kp;
            }
            union { uint4 u4; h16 h[8]; } w0, w1;
            w0.u4 = *(const uint4*)src;
            w1.u4 = *(const uint4*)(src + 8);
            #pragma unroll
            for (int i = 0; i < 8; ++i) {
                sA[rr * 68 + kp + i]     = (float)w0.h[i];
                sA[rr * 68 + kp + 8 + i] = (float)w1.h[i];
            }
        }
        for (int e = tid; e < 64 * 48; e += NTHR) {
            int kk = e / 48, c = e - kk * 48;
            sB[e] = (c < NC) ? Wfc[(k0 + kk) * NC + c] : 0.f;
        }
        __syncthreads();
        for (int kk = 0; kk < 64; ++kk) {
            float b0 = sB[kk * 48 + c0 + 0];
            float b1 = sB[kk * 48 + c0 + 1];
            float b2 = sB[kk * 48 + c0 + 2];
            #pragma unroll
            for (int i = 0; i < 4; ++i) {
                float av = sA[(rg * 4 + i) * 68 + kk];
                acc[i][0] += av * b0; acc[i][1] += av * b1; acc[i][2] += av * b2;
            }
        }
        __syncthreads();
    }
    #pragma unroll
    for (int i = 0; i < 4; ++i) {
        int r = blk * 64 + rg * 4 + i;
        #pragma unroll
        for (int jj = 0; jj < 3; ++jj) {
            int c = c0 + jj;
            if (c < NC) out[r * NC + c] = acc[i][jj] + bfc[c];
        }
    }
}

extern "C" void kernel_launch(void* const* d_in, const int* in_sizes, int n_in,
                              void* d_out, int out_size, void* d_ws, size_t ws_size,
                              hipStream_t stream) {
    const float* x      = (const float*)d_in[0];
    const float* rx     = (const float*)d_in[1];
    const int*   pad    = (const int*)d_in[2];
    const float* Wemb   = (const float*)d_in[4];
    const float* bemb   = (const float*)d_in[5];
    const float* Wx_l2r = (const float*)d_in[6];
    const float* bx_l2r = (const float*)d_in[7];
    const float* Wh_l2r = (const float*)d_in[8];
    const float* bh_l2r = (const float*)d_in[9];
    const float* Wx_r2l = (const float*)d_in[10];
    const float* bx_r2l = (const float*)d_in[11];
    const float* Wh_r2l = (const float*)d_in[12];
    const float* bh_r2l = (const float*)d_in[13];
    const float* lng    = (const float*)d_in[14];
    const float* lnb    = (const float*)d_in[15];
    const float* Wfc    = (const float*)d_in[16];
    const float* bfc    = (const float*)d_in[17];

    char* base = (char*)d_ws;
    size_t off = 0;
    auto alloc = [&](size_t bytes) { char* p = base + off; off += (bytes + 255) & ~(size_t)255; return p; };
    h16*   zx0f  = (h16*)  alloc((size_t)2 * Tdim * 32 * 8 * 64 * 4 * 2);
    h16*   h2    = (h16*)  alloc((size_t)2 * Tdim * Bdim * Hdim * 2);
    h16*   Wfrag = (h16*)  alloc((size_t)6 * 16 * 32768 * 2);
    h16*   W0f   = (h16*)  alloc((size_t)2 * 32 * 10 * 64 * 8 * 2);
    h16*   hfrag = (h16*)  alloc((size_t)6 * 4 * 65536 * 2);
    float* psum  = (float*)alloc((size_t)6 * Bdim * 16 * 4);
    float* psq   = (float*)alloc((size_t)6 * Bdim * 16 * 4);
    float* W0    = (float*)alloc((size_t)2 * KXdim * Hdim * 4);
    float* cb    = (float*)alloc((size_t)2 * 3 * Hdim * 4);
    int*   zdone = (int*)  alloc(6 * 32 * 4);
    int*   hdone = (int*)  alloc(6 * 32 * 4);

    prep1_kernel<<<(2 * KXdim * Hdim + 2 * 3 * Hdim) / NTHR, NTHR, 0, stream>>>(
        Wemb, bemb, Wx_l2r, bx_l2r, bh_l2r, Wx_r2l, bx_r2l, bh_r2l, W0, cb);

    pack_W_kernel<<<(6 * 16 * 32 * 2 * 64 * 8) / NTHR, NTHR, 0, stream>>>(
        W0, Wx_l2r, Wh_l2r, Wx_r2l, Wh_r2l, Wfrag);

    pack_W0f_kernel<<<(2 * 32 * 10 * 64 * 8) / NTHR, NTHR, 0, stream>>>(W0, W0f);

    zx0_kernel<<<1024, NTHR, 0, stream>>>(x, rx, W0f, cb, zx0f);

    zeroinit_kernel<<<(6 * 8192 + NTHR - 1) / NTHR, NTHR, 0, stream>>>(
        (uint4*)hfrag, zdone, hdone);

    PipeArgs a;
    a.Wfrag = Wfrag; a.zx0f = zx0f; a.cb = cb; a.lng = lng; a.lnb = lnb;
    a.hfrag = hfrag; a.h2 = h2; a.psum = psum; a.psq = psq;
    a.zdone = zdone; a.hdone = hdone;
    void* kargs[] = { &a };
    hipLaunchCooperativeKernel((void*)rnn_pipe, dim3(NTHR), dim3(NTHR), kargs, 0, stream);

    fc_kernel<<<(Bdim * Tdim) / 64, NTHR, 0, stream>>>(h2, pad, Wfc, bfc, (float*)d_out);
}